// Round 8
// baseline (663.779 us; speedup 1.0000x reference)
//
#include <hip/hip_runtime.h>
#include <hip/hip_fp16.h>

// Instant-NGP grid encoder, MI355X (gfx950).
// N=2,000,000 points [N,3] f32 in [0,1); 12 levels, F=2; out [N,24] f32.
// res: 16,23,32,46,64,92,128,184,256,368,512,736; hash iff r^3>2^19
// (levels 5..11, each exactly 2^19 entries -> & 0x7FFFF). Dense: no modulo.
//
// Round-7b: PAIR-TABLES + point-per-lane (no shuffles).
//   Round-6 counters: dense_kernel 171us VALU/shuffle-bound (corner-per-lane
//   = 8x redundant VALU) + 2.4x write amplification from lane0-only stores.
//   Now: ws pair table pair[i] = (pk(T[i]), pk(T[partner])), partner = i+1
//   (dense, x-neighbor adjacent) or i^1 (hash: h(ix+1)=h(ix)^1 for even ix).
//   Point-per-lane: dense = 4 aligned 8B gathers/level; hash = 4 pair
//   gathers + 4 exec-masked gathers for odd-ix lanes only. All stores
//   coalesced (hash PPT=2 -> 8B/thread).
//   (7b: nontemporal builtin can't take float2* -> scalar component loads.)

namespace {
constexpr int NLEV = 12;
constexpr int BLOCK = 256;
constexpr int HOFF = 408512;  // first hash-level offset (levels 5..11)
constexpr unsigned P1 = 2654435761u;
constexpr unsigned P2 = 805459861u;
constexpr unsigned HMASK = (1u << 19) - 1u;

__device__ __constant__ constexpr int kRes[NLEV] = {
    16, 23, 32, 46, 64, 92, 128, 184, 256, 368, 512, 736};
__device__ __constant__ constexpr int kOff[NLEV] = {
    0, 4096, 16264, 49032, 146368, 408512,
    932800, 1457088, 1981376, 2505664, 3029952, 3554240};

__device__ __forceinline__ unsigned pkh2(float a, float b) {
    __half2 h = __floats2half2_rn(a, b);
    return *reinterpret_cast<unsigned*>(&h);
}
__device__ __forceinline__ float lo2f(unsigned u) {
    __half2 h = *reinterpret_cast<__half2*>(&u);
    return __low2float(h);
}
__device__ __forceinline__ float hi2f(unsigned u) {
    __half2 h = *reinterpret_cast<__half2*>(&u);
    return __high2float(h);
}
}  // namespace

// ---- pack pair table: pair[i] = (pk(e[i]), pk(e[i+1 or i^1])) ----
__global__ void __launch_bounds__(BLOCK)
pack_pair_kernel(const float2* __restrict__ emb, uint2* __restrict__ pairs,
                 int total)
{
    int i = blockIdx.x * BLOCK + threadIdx.x;
    if (i >= total) return;
    float2 v = emb[i];
    int j = (i < HOFF) ? (i + 1) : (i ^ 1);
    float2 w = emb[j];
    __builtin_nontemporal_store(pkh2(v.x, v.y), &pairs[i].x);
    __builtin_nontemporal_store(pkh2(w.x, w.y), &pairs[i].y);
}

// ---- pack plain fp16x2 table (fallback path) ----
__global__ void __launch_bounds__(BLOCK)
pack_table_kernel(const float2* __restrict__ emb,
                  unsigned* __restrict__ packed, int total)
{
    int i = blockIdx.x * BLOCK + threadIdx.x;
    if (i < total) {
        float2 v = emb[i];
        packed[i] = pkh2(v.x, v.y);
    }
}

// ---- fused dense levels 0..4, point-per-lane ----
template <int PAIRED>
__global__ void __launch_bounds__(BLOCK)
dense_kernel(const float* __restrict__ inp, const void* __restrict__ tab,
             unsigned* __restrict__ stage, int N)
{
    const int n = blockIdx.x * BLOCK + threadIdx.x;
    if (n >= N) return;
    const float x = __builtin_nontemporal_load(&inp[3 * n + 0]);
    const float y = __builtin_nontemporal_load(&inp[3 * n + 1]);
    const float z = __builtin_nontemporal_load(&inp[3 * n + 2]);

#pragma unroll
    for (int l = 0; l < 5; ++l) {
        const unsigned R = (unsigned)kRes[l];          // folds after unroll
        const float scale = (float)(kRes[l] - 1);
        const float px = x * scale, py = y * scale, pz = z * scale;
        const float fx = floorf(px), fy = floorf(py), fz = floorf(pz);
        const float rx = px - fx, ry = py - fy, rz = pz - fz;
        const unsigned ix = (unsigned)fx, iy = (unsigned)fy, iz = (unsigned)fz;
        const unsigned base = ix + iy * R + iz * R * R;

        const float w0y = 1.0f - ry, w0z = 1.0f - rz;
        const float wx0 = 1.0f - rx, wx1 = rx;
        float sx = 0.0f, sy = 0.0f;

        if (PAIRED) {
            const uint2* pt = reinterpret_cast<const uint2*>(tab) + kOff[l];
            const uint2 q00 = pt[base];
            const uint2 q10 = pt[base + R];
            const uint2 q01 = pt[base + R * R];
            const uint2 q11 = pt[base + R + R * R];
            const float wp00 = w0y * w0z, wp10 = ry * w0z;
            const float wp01 = w0y * rz,  wp11 = ry * rz;
            {
                float a = wp00 * wx0, b = wp00 * wx1;
                sx = fmaf(a, lo2f(q00.x), fmaf(b, lo2f(q00.y), sx));
                sy = fmaf(a, hi2f(q00.x), fmaf(b, hi2f(q00.y), sy));
            }
            {
                float a = wp10 * wx0, b = wp10 * wx1;
                sx = fmaf(a, lo2f(q10.x), fmaf(b, lo2f(q10.y), sx));
                sy = fmaf(a, hi2f(q10.x), fmaf(b, hi2f(q10.y), sy));
            }
            {
                float a = wp01 * wx0, b = wp01 * wx1;
                sx = fmaf(a, lo2f(q01.x), fmaf(b, lo2f(q01.y), sx));
                sy = fmaf(a, hi2f(q01.x), fmaf(b, hi2f(q01.y), sy));
            }
            {
                float a = wp11 * wx0, b = wp11 * wx1;
                sx = fmaf(a, lo2f(q11.x), fmaf(b, lo2f(q11.y), sx));
                sy = fmaf(a, hi2f(q11.x), fmaf(b, hi2f(q11.y), sy));
            }
        } else {
            const unsigned* pt = reinterpret_cast<const unsigned*>(tab) + kOff[l];
            unsigned e[8];
            e[0] = pt[base];
            e[1] = pt[base + 1];
            e[2] = pt[base + R];
            e[3] = pt[base + R + 1];
            e[4] = pt[base + R * R];
            e[5] = pt[base + R * R + 1];
            e[6] = pt[base + R + R * R];
            e[7] = pt[base + R + R * R + 1];
            const float wt[8] = {w0y * w0z * wx0, w0y * w0z * wx1,
                                 ry * w0z * wx0,  ry * w0z * wx1,
                                 w0y * rz * wx0,  w0y * rz * wx1,
                                 ry * rz * wx0,   ry * rz * wx1};
#pragma unroll
            for (int c = 0; c < 8; ++c) {
                sx = fmaf(wt[c], lo2f(e[c]), sx);
                sy = fmaf(wt[c], hi2f(e[c]), sy);
            }
        }
        __builtin_nontemporal_store(pkh2(sx, sy), &stage[(long long)l * N + n]);
    }
}

// ---- one hash level, point-per-lane ----
template <int L, int PAIRED>
__device__ __forceinline__ unsigned
encode_hash(float x, float y, float z, const void* __restrict__ tab)
{
    const float scale = (float)(kRes[L] - 1);
    const float px = x * scale, py = y * scale, pz = z * scale;
    const float fx = floorf(px), fy = floorf(py), fz = floorf(pz);
    const float rx = px - fx, ry = py - fy, rz = pz - fz;
    const unsigned ix = (unsigned)fx, iy = (unsigned)fy, iz = (unsigned)fz;
    const unsigned y0 = iy * P1, y1 = y0 + P1;
    const unsigned z0 = iz * P2, z1 = z0 + P2;
    const unsigned i00 = (ix ^ y0 ^ z0) & HMASK;
    const unsigned i10 = (ix ^ y1 ^ z0) & HMASK;
    const unsigned i01 = (ix ^ y0 ^ z1) & HMASK;
    const unsigned i11 = (ix ^ y1 ^ z1) & HMASK;

    unsigned b0[4], b1[4];

    if (PAIRED) {
        const uint2* pt = reinterpret_cast<const uint2*>(tab) + kOff[L];
        const uint2 q00 = pt[i00];
        const uint2 q10 = pt[i10];
        const uint2 q01 = pt[i01];
        const uint2 q11 = pt[i11];
        b0[0] = q00.x; b0[1] = q10.x; b0[2] = q01.x; b0[3] = q11.x;
        // even ix: hash(ix+1) = idx ^ 1 -> second half of the pair word
        b1[0] = q00.y; b1[1] = q10.y; b1[2] = q01.y; b1[3] = q11.y;
        if (ix & 1u) {  // odd ix: recompute, exec-masked gathers
            const unsigned xo = ix + 1u;
            b1[0] = pt[(xo ^ y0 ^ z0) & HMASK].x;
            b1[1] = pt[(xo ^ y1 ^ z0) & HMASK].x;
            b1[2] = pt[(xo ^ y0 ^ z1) & HMASK].x;
            b1[3] = pt[(xo ^ y1 ^ z1) & HMASK].x;
        }
    } else {
        const unsigned* pt = reinterpret_cast<const unsigned*>(tab) + kOff[L];
        const unsigned xo = ix + 1u;
        b0[0] = pt[i00];
        b0[1] = pt[i10];
        b0[2] = pt[i01];
        b0[3] = pt[i11];
        b1[0] = pt[(xo ^ y0 ^ z0) & HMASK];
        b1[1] = pt[(xo ^ y1 ^ z0) & HMASK];
        b1[2] = pt[(xo ^ y0 ^ z1) & HMASK];
        b1[3] = pt[(xo ^ y1 ^ z1) & HMASK];
    }

    const float w0y = 1.0f - ry, w0z = 1.0f - rz;
    const float wp[4] = {w0y * w0z, ry * w0z, w0y * rz, ry * rz};
    const float wx0 = 1.0f - rx, wx1 = rx;
    float sx = 0.0f, sy = 0.0f;
#pragma unroll
    for (int c = 0; c < 4; ++c) {
        const float a = wp[c] * wx0, b = wp[c] * wx1;
        sx = fmaf(a, lo2f(b0[c]), fmaf(b, lo2f(b1[c]), sx));
        sy = fmaf(a, hi2f(b0[c]), fmaf(b, hi2f(b1[c]), sy));
    }
    return pkh2(sx, sy);
}

template <int L, int PAIRED>
__global__ void __launch_bounds__(BLOCK)
level_kernel(const float* __restrict__ inp, const void* __restrict__ tab,
             unsigned* __restrict__ stage_l, int N)
{
    const long long tid = (long long)blockIdx.x * BLOCK + threadIdx.x;
    const long long p0 = tid * 2;
    if (p0 >= N) return;

    // 6 consecutive floats (2 points) per thread: coalesced component loads
    const long long fb = 6 * tid;
    const float x0 = __builtin_nontemporal_load(&inp[fb + 0]);
    const float y0f = __builtin_nontemporal_load(&inp[fb + 1]);
    const float z0f = __builtin_nontemporal_load(&inp[fb + 2]);
    const float x1 = __builtin_nontemporal_load(&inp[fb + 3]);
    const float y1f = __builtin_nontemporal_load(&inp[fb + 4]);
    const float z1f = __builtin_nontemporal_load(&inp[fb + 5]);

    const unsigned r0 = encode_hash<L, PAIRED>(x0, y0f, z0f, tab);
    const unsigned r1 = encode_hash<L, PAIRED>(x1, y1f, z1f, tab);

    if (p0 + 1 < N) {
        __builtin_nontemporal_store(r0, &stage_l[p0]);
        __builtin_nontemporal_store(r1, &stage_l[p0 + 1]);
    } else {
        __builtin_nontemporal_store(r0, &stage_l[p0]);
    }
}

// ---- final: [12][N] fp16x2 -> [N][24] f32, LDS transpose ----
__global__ void __launch_bounds__(BLOCK)
assemble_kernel(const unsigned* __restrict__ lvl, float* __restrict__ out,
                int N)
{
    __shared__ float s_out[BLOCK * 25];
    const int t = threadIdx.x;
    const int n = blockIdx.x * BLOCK + t;

    if (n < N) {
#pragma unroll
        for (int l = 0; l < NLEV; ++l) {
            unsigned u = __builtin_nontemporal_load(&lvl[(long long)l * N + n]);
            s_out[t * 25 + 2 * l + 0] = lo2f(u);
            s_out[t * 25 + 2 * l + 1] = hi2f(u);
        }
    }
    __syncthreads();

    const long long base = (long long)blockIdx.x * (BLOCK * 24);
    const long long lim = (long long)N * 24;
#pragma unroll
    for (int k = 0; k < 24; ++k) {
        const int g = k * BLOCK + t;
        const long long gg = base + g;
        if (gg < lim) {
            const int nl = g / 24;   // magic-mul division
            const int j = g - nl * 24;
            __builtin_nontemporal_store(s_out[nl * 25 + j], &out[gg]);
        }
    }
}

// ---- fallback: fused single-kernel (ws too small for staging) ----
template <int PACKED>
__global__ void __launch_bounds__(BLOCK, 4)
fused_kernel(const float* __restrict__ inp, const void* __restrict__ table,
             float* __restrict__ out, int N)
{
    __shared__ float s_out[BLOCK * 25];
    const int t = threadIdx.x;
    const int n = blockIdx.x * BLOCK + t;

    if (n < N) {
        const float x = inp[n * 3 + 0];
        const float y = inp[n * 3 + 1];
        const float z = inp[n * 3 + 2];

#pragma unroll
        for (int l = 0; l < NLEV; ++l) {
            const int R = kRes[l];
            const bool HASH = (l >= 5);
            const float scale = (float)(R - 1);
            const float px = x * scale, py = y * scale, pz = z * scale;
            const float fx = floorf(px), fy = floorf(py), fz = floorf(pz);
            const float wx = px - fx, wy = py - fy, wz = pz - fz;
            const unsigned ix = (unsigned)fx, iy = (unsigned)fy,
                           iz = (unsigned)fz;
            unsigned x0, x1, y0, y1, z0, z1;
            if (HASH) {
                x0 = ix;      x1 = ix + 1u;
                y0 = iy * P1; y1 = y0 + P1;
                z0 = iz * P2; z1 = z0 + P2;
            } else {
                const unsigned Ru = (unsigned)R, R2 = Ru * Ru;
                x0 = ix;      x1 = ix + 1u;
                y0 = iy * Ru; y1 = y0 + Ru;
                z0 = iz * R2; z1 = z0 + R2;
            }
            unsigned idx[8];
            if (HASH) {
                idx[0] = (x0 ^ y0 ^ z0) & HMASK; idx[1] = (x1 ^ y0 ^ z0) & HMASK;
                idx[2] = (x0 ^ y1 ^ z0) & HMASK; idx[3] = (x1 ^ y1 ^ z0) & HMASK;
                idx[4] = (x0 ^ y0 ^ z1) & HMASK; idx[5] = (x1 ^ y0 ^ z1) & HMASK;
                idx[6] = (x0 ^ y1 ^ z1) & HMASK; idx[7] = (x1 ^ y1 ^ z1) & HMASK;
            } else {
                idx[0] = x0 + y0 + z0; idx[1] = x1 + y0 + z0;
                idx[2] = x0 + y1 + z0; idx[3] = x1 + y1 + z0;
                idx[4] = x0 + y0 + z1; idx[5] = x1 + y0 + z1;
                idx[6] = x0 + y1 + z1; idx[7] = x1 + y1 + z1;
            }
            float ex[8], ey[8];
            if (PACKED) {
                const unsigned* eb =
                    reinterpret_cast<const unsigned*>(table) + kOff[l];
#pragma unroll
                for (int c = 0; c < 8; ++c) {
                    unsigned uu = eb[idx[c]];
                    ex[c] = lo2f(uu); ey[c] = hi2f(uu);
                }
            } else {
                const float2* eb =
                    reinterpret_cast<const float2*>(table) + kOff[l];
#pragma unroll
                for (int c = 0; c < 8; ++c) {
                    float2 e = eb[idx[c]]; ex[c] = e.x; ey[c] = e.y;
                }
            }
            const float w0x = 1.0f - wx, w0y = 1.0f - wy, w0z = 1.0f - wz;
            const float w00 = w0x * w0y, w10 = wx * w0y;
            const float w01 = w0x * wy,  w11 = wx * wy;
            const float wt[8] = {w00 * w0z, w10 * w0z, w01 * w0z, w11 * w0z,
                                 w00 * wz,  w10 * wz,  w01 * wz,  w11 * wz};
            float sx = 0.0f, sy = 0.0f;
#pragma unroll
            for (int c = 0; c < 8; ++c) {
                sx = fmaf(wt[c], ex[c], sx);
                sy = fmaf(wt[c], ey[c], sy);
            }
            s_out[t * 25 + 2 * l + 0] = sx;
            s_out[t * 25 + 2 * l + 1] = sy;
        }
    }
    __syncthreads();
    const long long base = (long long)blockIdx.x * (BLOCK * 24);
    const long long lim = (long long)N * 24;
#pragma unroll
    for (int k = 0; k < 24; ++k) {
        const int g = k * BLOCK + t;
        const long long gg = base + g;
        if (gg < lim) {
            const int nl = g / 24;
            const int j = g - nl * 24;
            out[gg] = s_out[nl * 25 + j];
        }
    }
}

extern "C" void kernel_launch(void* const* d_in, const int* in_sizes, int n_in,
                              void* d_out, int out_size, void* d_ws, size_t ws_size,
                              hipStream_t stream) {
    const float* inputs = (const float*)d_in[0];
    const float* embeddings = (const float*)d_in[1];
    // d_in[2]/d_in[3] (offsets/resolutions) are compile-time constants here.
    float* out = (float*)d_out;

    const int N = in_sizes[0] / 3;            // 2,000,000
    const int total = in_sizes[1] / 2;        // 4,078,528 table entries

    const size_t pair_bytes = (size_t)total * sizeof(uint2);      // 32.6 MB
    const size_t packed_bytes = (size_t)total * sizeof(unsigned); // 16.3 MB
    const size_t stage_bytes = (size_t)NLEV * N * sizeof(unsigned); // 96 MB

    const int pgrid = (total + BLOCK - 1) / BLOCK;
    const int ngrid = (N + BLOCK - 1) / BLOCK;
    const int hgrid = (N / 2 + BLOCK - 1) / BLOCK;  // PPT=2

    if (ws_size >= pair_bytes + stage_bytes) {
        uint2* pairs = (uint2*)d_ws;
        unsigned* stage = (unsigned*)(pairs + total);
        pack_pair_kernel<<<pgrid, BLOCK, 0, stream>>>(
            (const float2*)embeddings, pairs, total);
        dense_kernel<1><<<ngrid, BLOCK, 0, stream>>>(inputs, pairs, stage, N);
        level_kernel<5,  1><<<hgrid, BLOCK, 0, stream>>>(inputs, pairs, stage + 5LL * N, N);
        level_kernel<6,  1><<<hgrid, BLOCK, 0, stream>>>(inputs, pairs, stage + 6LL * N, N);
        level_kernel<7,  1><<<hgrid, BLOCK, 0, stream>>>(inputs, pairs, stage + 7LL * N, N);
        level_kernel<8,  1><<<hgrid, BLOCK, 0, stream>>>(inputs, pairs, stage + 8LL * N, N);
        level_kernel<9,  1><<<hgrid, BLOCK, 0, stream>>>(inputs, pairs, stage + 9LL * N, N);
        level_kernel<10, 1><<<hgrid, BLOCK, 0, stream>>>(inputs, pairs, stage + 10LL * N, N);
        level_kernel<11, 1><<<hgrid, BLOCK, 0, stream>>>(inputs, pairs, stage + 11LL * N, N);
        assemble_kernel<<<ngrid, BLOCK, 0, stream>>>(stage, out, N);
    } else if (ws_size >= packed_bytes + stage_bytes) {
        unsigned* packed = (unsigned*)d_ws;
        unsigned* stage = packed + total;
        pack_table_kernel<<<pgrid, BLOCK, 0, stream>>>(
            (const float2*)embeddings, packed, total);
        dense_kernel<0><<<ngrid, BLOCK, 0, stream>>>(inputs, packed, stage, N);
        level_kernel<5,  0><<<hgrid, BLOCK, 0, stream>>>(inputs, packed, stage + 5LL * N, N);
        level_kernel<6,  0><<<hgrid, BLOCK, 0, stream>>>(inputs, packed, stage + 6LL * N, N);
        level_kernel<7,  0><<<hgrid, BLOCK, 0, stream>>>(inputs, packed, stage + 7LL * N, N);
        level_kernel<8,  0><<<hgrid, BLOCK, 0, stream>>>(inputs, packed, stage + 8LL * N, N);
        level_kernel<9,  0><<<hgrid, BLOCK, 0, stream>>>(inputs, packed, stage + 9LL * N, N);
        level_kernel<10, 0><<<hgrid, BLOCK, 0, stream>>>(inputs, packed, stage + 10LL * N, N);
        level_kernel<11, 0><<<hgrid, BLOCK, 0, stream>>>(inputs, packed, stage + 11LL * N, N);
        assemble_kernel<<<ngrid, BLOCK, 0, stream>>>(stage, out, N);
    } else if (ws_size >= packed_bytes) {
        unsigned* packed = (unsigned*)d_ws;
        pack_table_kernel<<<pgrid, BLOCK, 0, stream>>>(
            (const float2*)embeddings, packed, total);
        fused_kernel<1><<<ngrid, BLOCK, 0, stream>>>(inputs, packed, out, N);
    } else {
        fused_kernel<0><<<ngrid, BLOCK, 0, stream>>>(inputs, embeddings, out, N);
    }
}

// Round 9
// 530.185 us; speedup vs baseline: 1.2520x; 1.2520x over previous
//
#include <hip/hip_runtime.h>
#include <hip/hip_fp16.h>

// Instant-NGP grid encoder, MI355X (gfx950).
// N=2,000,000 points [N,3] f32 in [0,1); 12 levels, F=2; out [N,24] f32.
// res: 16,23,32,46,64,92,128,184,256,368,512,736; hash iff r^3>2^19
// (levels 5..11, each exactly 2^19 entries -> & 0x7FFFF). Dense: no modulo.
//
// Round-9: aligned-pair hash on the 2MB packed table + quad/pair dense split.
//   Round-8 lesson: 8B pair table = 4MB/hash level = entire XCD L2 -> thrash
//   (hash 43 -> 65us). Fix: keep 4B packed table; for even ix the x-pair
//   {h, h^1} is one ALIGNED uint2 at packed[h>>1] (h(ix+1)=h(ix)^1). Odd-ix
//   lanes add 4 exec-masked 4B gathers. Dense: levels 0-3 quad table (16B
//   entries, 2.34MB total, 2 gathers/pt/level); level 4 separate dispatch
//   with 2MB pair table. Inputs cacheable (L3-reused across 9 dispatches).

namespace {
constexpr int NLEV = 12;
constexpr int BLOCK = 256;
constexpr int TOTAL = 4078528;        // table entries
constexpr int DENSE_A_END = 146368;   // levels 0..3
constexpr int L4_SIZE = 262144;       // level 4 (64^3)
constexpr unsigned P1 = 2654435761u;
constexpr unsigned P2 = 805459861u;
constexpr unsigned HMASK = (1u << 19) - 1u;

__device__ __constant__ constexpr int kRes[NLEV] = {
    16, 23, 32, 46, 64, 92, 128, 184, 256, 368, 512, 736};
__device__ __constant__ constexpr int kOff[NLEV] = {
    0, 4096, 16264, 49032, 146368, 408512,
    932800, 1457088, 1981376, 2505664, 3029952, 3554240};

typedef float    f32x2 __attribute__((ext_vector_type(2)));
typedef unsigned u32x2 __attribute__((ext_vector_type(2)));

__device__ __forceinline__ unsigned pkh2(float a, float b) {
    __half2 h = __floats2half2_rn(a, b);
    return *reinterpret_cast<unsigned*>(&h);
}
__device__ __forceinline__ float lo2f(unsigned u) {
    __half2 h = *reinterpret_cast<__half2*>(&u);
    return __low2float(h);
}
__device__ __forceinline__ float hi2f(unsigned u) {
    __half2 h = *reinterpret_cast<__half2*>(&u);
    return __high2float(h);
}
}  // namespace

// ---- pack full fp16x2 table (hash levels + fallback) ----
__global__ void __launch_bounds__(BLOCK)
pack_table_kernel(const float2* __restrict__ emb,
                  unsigned* __restrict__ packed, int total)
{
    int i = blockIdx.x * BLOCK + threadIdx.x;
    if (i < total) {
        float2 v = emb[i];
        packed[i] = pkh2(v.x, v.y);
    }
}

// ---- quad table for dense levels 0..3: (e[i], e[i+1], e[i+R], e[i+R+1]) ----
__global__ void __launch_bounds__(BLOCK)
pack_quad_kernel(const float2* __restrict__ emb, uint4* __restrict__ quad)
{
    int i = blockIdx.x * BLOCK + threadIdx.x;
    if (i >= DENSE_A_END) return;
    int R = (i < 4096) ? 16 : (i < 16264) ? 23 : (i < 49032) ? 32 : 46;
    float2 e0 = emb[i];
    float2 e1 = emb[i + 1];
    float2 e2 = emb[i + R];
    float2 e3 = emb[i + R + 1];         // stays < TOTAL for all i here
    uint4 q;
    q.x = pkh2(e0.x, e0.y); q.y = pkh2(e1.x, e1.y);
    q.z = pkh2(e2.x, e2.y); q.w = pkh2(e3.x, e3.y);
    quad[i] = q;
}

// ---- pair table for dense level 4: (e[g], e[g+1]) ----
__global__ void __launch_bounds__(BLOCK)
pack_pair4_kernel(const float2* __restrict__ emb, u32x2* __restrict__ pair4)
{
    int i = blockIdx.x * BLOCK + threadIdx.x;
    if (i >= L4_SIZE) return;
    int g = DENSE_A_END + i;
    float2 a = emb[g];
    float2 b = emb[g + 1];              // g+1 <= 408512 < TOTAL
    u32x2 o;
    o.x = pkh2(a.x, a.y);
    o.y = pkh2(b.x, b.y);
    pair4[i] = o;
}

// ---- dense levels 0..3, PPT=2, quad gathers ----
__global__ void __launch_bounds__(BLOCK)
dense_a_kernel(const float* __restrict__ inp, const uint4* __restrict__ quad,
               unsigned* __restrict__ stage, int N)
{
    const int tid = blockIdx.x * BLOCK + threadIdx.x;
    const int p0 = 2 * tid;
    if (p0 >= N) return;

    const f32x2* ip2 = reinterpret_cast<const f32x2*>(inp);
    const f32x2 v0 = ip2[3 * tid + 0];  // x0 y0
    const f32x2 v1 = ip2[3 * tid + 1];  // z0 x1
    const f32x2 v2 = ip2[3 * tid + 2];  // y1 z1
    const float X[2] = {v0.x, v1.y};
    const float Y[2] = {v0.y, v2.x};
    const float Z[2] = {v1.x, v2.y};

#pragma unroll
    for (int l = 0; l < 4; ++l) {
        const unsigned R = (unsigned)kRes[l];
        const unsigned R2 = R * R;
        const float scale = (float)(kRes[l] - 1);
        const uint4* qt = quad + kOff[l];
        u32x2 res;
#pragma unroll
        for (int k = 0; k < 2; ++k) {
            const float px = X[k] * scale, py = Y[k] * scale, pz = Z[k] * scale;
            const float fx = floorf(px), fy = floorf(py), fz = floorf(pz);
            const float rx = px - fx, ry = py - fy, rz = pz - fz;
            const unsigned ix = (unsigned)fx, iy = (unsigned)fy,
                           iz = (unsigned)fz;
            const unsigned base = ix + iy * R + iz * R2;
            const uint4 q0 = qt[base];        // z = iz
            const uint4 q1 = qt[base + R2];   // z = iz+1
            const float wx0 = 1.0f - rx, wx1 = rx;
            const float wy0 = 1.0f - ry, wy1 = ry;
            const float wz0 = 1.0f - rz, wz1 = rz;
            const float ex00 = wx0 * lo2f(q0.x) + wx1 * lo2f(q0.y);
            const float ey00 = wx0 * hi2f(q0.x) + wx1 * hi2f(q0.y);
            const float ex10 = wx0 * lo2f(q0.z) + wx1 * lo2f(q0.w);
            const float ey10 = wx0 * hi2f(q0.z) + wx1 * hi2f(q0.w);
            const float ex01 = wx0 * lo2f(q1.x) + wx1 * lo2f(q1.y);
            const float ey01 = wx0 * hi2f(q1.x) + wx1 * hi2f(q1.y);
            const float ex11 = wx0 * lo2f(q1.z) + wx1 * lo2f(q1.w);
            const float ey11 = wx0 * hi2f(q1.z) + wx1 * hi2f(q1.w);
            const float sx = wz0 * (wy0 * ex00 + wy1 * ex10) +
                             wz1 * (wy0 * ex01 + wy1 * ex11);
            const float sy = wz0 * (wy0 * ey00 + wy1 * ey10) +
                             wz1 * (wy0 * ey01 + wy1 * ey11);
            res[k] = pkh2(sx, sy);
        }
        if (p0 + 1 < N) {
            __builtin_nontemporal_store(
                res, reinterpret_cast<u32x2*>(&stage[(long long)l * N + p0]));
        } else {
            __builtin_nontemporal_store(res.x, &stage[(long long)l * N + p0]);
        }
    }
}

// ---- dense level 4 (64^3), PPT=2, pair gathers ----
__global__ void __launch_bounds__(BLOCK)
dense_b_kernel(const float* __restrict__ inp, const u32x2* __restrict__ pair4,
               unsigned* __restrict__ stage4, int N)
{
    const int tid = blockIdx.x * BLOCK + threadIdx.x;
    const int p0 = 2 * tid;
    if (p0 >= N) return;

    const f32x2* ip2 = reinterpret_cast<const f32x2*>(inp);
    const f32x2 v0 = ip2[3 * tid + 0];
    const f32x2 v1 = ip2[3 * tid + 1];
    const f32x2 v2 = ip2[3 * tid + 2];
    const float X[2] = {v0.x, v1.y};
    const float Y[2] = {v0.y, v2.x};
    const float Z[2] = {v1.x, v2.y};

    constexpr unsigned R = 64, R2 = 4096;
    constexpr float scale = 63.0f;
    u32x2 res;
#pragma unroll
    for (int k = 0; k < 2; ++k) {
        const float px = X[k] * scale, py = Y[k] * scale, pz = Z[k] * scale;
        const float fx = floorf(px), fy = floorf(py), fz = floorf(pz);
        const float rx = px - fx, ry = py - fy, rz = pz - fz;
        const unsigned ix = (unsigned)fx, iy = (unsigned)fy, iz = (unsigned)fz;
        const unsigned base = ix + iy * R + iz * R2;
        const u32x2 q00 = pair4[base];
        const u32x2 q10 = pair4[base + R];
        const u32x2 q01 = pair4[base + R2];
        const u32x2 q11 = pair4[base + R2 + R];
        const float wx0 = 1.0f - rx, wx1 = rx;
        const float wy0 = 1.0f - ry, wy1 = ry;
        const float wz0 = 1.0f - rz, wz1 = rz;
        const float w00 = wy0 * wz0, w10 = wy1 * wz0;
        const float w01 = wy0 * wz1, w11 = wy1 * wz1;
        float sx = 0.0f, sy = 0.0f;
        sx = fmaf(w00 * wx0, lo2f(q00.x), fmaf(w00 * wx1, lo2f(q00.y), sx));
        sy = fmaf(w00 * wx0, hi2f(q00.x), fmaf(w00 * wx1, hi2f(q00.y), sy));
        sx = fmaf(w10 * wx0, lo2f(q10.x), fmaf(w10 * wx1, lo2f(q10.y), sx));
        sy = fmaf(w10 * wx0, hi2f(q10.x), fmaf(w10 * wx1, hi2f(q10.y), sy));
        sx = fmaf(w01 * wx0, lo2f(q01.x), fmaf(w01 * wx1, lo2f(q01.y), sx));
        sy = fmaf(w01 * wx0, hi2f(q01.x), fmaf(w01 * wx1, hi2f(q01.y), sy));
        sx = fmaf(w11 * wx0, lo2f(q11.x), fmaf(w11 * wx1, lo2f(q11.y), sx));
        sy = fmaf(w11 * wx0, hi2f(q11.x), fmaf(w11 * wx1, hi2f(q11.y), sy));
        res[k] = pkh2(sx, sy);
    }
    if (p0 + 1 < N) {
        __builtin_nontemporal_store(res, reinterpret_cast<u32x2*>(&stage4[p0]));
    } else {
        __builtin_nontemporal_store(res.x, &stage4[p0]);
    }
}

// ---- one hash level, PPT=2, aligned-uint2 x-pairs on the 4B table ----
template <int L>
__device__ __forceinline__ unsigned
encode_hash(float x, float y, float z, const unsigned* __restrict__ pt)
{
    const float scale = (float)(kRes[L] - 1);
    const float px = x * scale, py = y * scale, pz = z * scale;
    const float fx = floorf(px), fy = floorf(py), fz = floorf(pz);
    const float rx = px - fx, ry = py - fy, rz = pz - fz;
    const unsigned ix = (unsigned)fx, iy = (unsigned)fy, iz = (unsigned)fz;
    const unsigned yA = iy * P1, yB = yA + P1;
    const unsigned zA = iz * P2, zB = zA + P2;
    const unsigned h00 = (ix ^ yA ^ zA) & HMASK;
    const unsigned h10 = (ix ^ yB ^ zA) & HMASK;
    const unsigned h01 = (ix ^ yA ^ zB) & HMASK;
    const unsigned h11 = (ix ^ yB ^ zB) & HMASK;

    const u32x2* pt2 = reinterpret_cast<const u32x2*>(pt);
    const u32x2 q00 = pt2[h00 >> 1];
    const u32x2 q10 = pt2[h10 >> 1];
    const u32x2 q01 = pt2[h01 >> 1];
    const u32x2 q11 = pt2[h11 >> 1];

    // own entry + sibling (= x-partner when ix is even)
    unsigned e00 = (h00 & 1) ? q00.y : q00.x;
    unsigned e10 = (h10 & 1) ? q10.y : q10.x;
    unsigned e01 = (h01 & 1) ? q01.y : q01.x;
    unsigned e11 = (h11 & 1) ? q11.y : q11.x;
    unsigned f00 = (h00 & 1) ? q00.x : q00.y;
    unsigned f10 = (h10 & 1) ? q10.x : q10.y;
    unsigned f01 = (h01 & 1) ? q01.x : q01.y;
    unsigned f11 = (h11 & 1) ? q11.x : q11.y;

    if (ix & 1u) {  // odd ix: sibling is ix-1, need real ix+1 entries
        const unsigned xo = ix + 1u;
        f00 = pt[(xo ^ yA ^ zA) & HMASK];
        f10 = pt[(xo ^ yB ^ zA) & HMASK];
        f01 = pt[(xo ^ yA ^ zB) & HMASK];
        f11 = pt[(xo ^ yB ^ zB) & HMASK];
    }

    const float wx0 = 1.0f - rx, wx1 = rx;
    const float wy0 = 1.0f - ry, wy1 = ry;
    const float wz0 = 1.0f - rz, wz1 = rz;
    const float w00 = wy0 * wz0, w10 = wy1 * wz0;
    const float w01 = wy0 * wz1, w11 = wy1 * wz1;
    float sx = 0.0f, sy = 0.0f;
    sx = fmaf(w00 * wx0, lo2f(e00), fmaf(w00 * wx1, lo2f(f00), sx));
    sy = fmaf(w00 * wx0, hi2f(e00), fmaf(w00 * wx1, hi2f(f00), sy));
    sx = fmaf(w10 * wx0, lo2f(e10), fmaf(w10 * wx1, lo2f(f10), sx));
    sy = fmaf(w10 * wx0, hi2f(e10), fmaf(w10 * wx1, hi2f(f10), sy));
    sx = fmaf(w01 * wx0, lo2f(e01), fmaf(w01 * wx1, lo2f(f01), sx));
    sy = fmaf(w01 * wx0, hi2f(e01), fmaf(w01 * wx1, hi2f(f01), sy));
    sx = fmaf(w11 * wx0, lo2f(e11), fmaf(w11 * wx1, lo2f(f11), sx));
    sy = fmaf(w11 * wx0, hi2f(e11), fmaf(w11 * wx1, hi2f(f11), sy));
    return pkh2(sx, sy);
}

template <int L>
__global__ void __launch_bounds__(BLOCK)
hash_kernel(const float* __restrict__ inp, const unsigned* __restrict__ packed,
            unsigned* __restrict__ stage_l, int N)
{
    const int tid = blockIdx.x * BLOCK + threadIdx.x;
    const int p0 = 2 * tid;
    if (p0 >= N) return;

    const f32x2* ip2 = reinterpret_cast<const f32x2*>(inp);
    const f32x2 v0 = ip2[3 * tid + 0];
    const f32x2 v1 = ip2[3 * tid + 1];
    const f32x2 v2 = ip2[3 * tid + 2];

    const unsigned* pt = packed + kOff[L];
    u32x2 res;
    res.x = encode_hash<L>(v0.x, v0.y, v1.x, pt);
    res.y = encode_hash<L>(v1.y, v2.x, v2.y, pt);

    if (p0 + 1 < N) {
        __builtin_nontemporal_store(res, reinterpret_cast<u32x2*>(&stage_l[p0]));
    } else {
        __builtin_nontemporal_store(res.x, &stage_l[p0]);
    }
}

// ---- final: [12][N] fp16x2 -> [N][24] f32, LDS transpose ----
__global__ void __launch_bounds__(BLOCK)
assemble_kernel(const unsigned* __restrict__ lvl, float* __restrict__ out,
                int N)
{
    __shared__ float s_out[BLOCK * 25];
    const int t = threadIdx.x;
    const int n = blockIdx.x * BLOCK + t;

    if (n < N) {
#pragma unroll
        for (int l = 0; l < NLEV; ++l) {
            unsigned u = __builtin_nontemporal_load(&lvl[(long long)l * N + n]);
            s_out[t * 25 + 2 * l + 0] = lo2f(u);
            s_out[t * 25 + 2 * l + 1] = hi2f(u);
        }
    }
    __syncthreads();

    const long long base = (long long)blockIdx.x * (BLOCK * 24);
    const long long lim = (long long)N * 24;
#pragma unroll
    for (int k = 0; k < 24; ++k) {
        const int g = k * BLOCK + t;
        const long long gg = base + g;
        if (gg < lim) {
            const int nl = g / 24;   // magic-mul division
            const int j = g - nl * 24;
            __builtin_nontemporal_store(s_out[nl * 25 + j], &out[gg]);
        }
    }
}

// ---- fallback: fused single-kernel (ws too small for staging) ----
template <int PACKED>
__global__ void __launch_bounds__(BLOCK, 4)
fused_kernel(const float* __restrict__ inp, const void* __restrict__ table,
             float* __restrict__ out, int N)
{
    __shared__ float s_out[BLOCK * 25];
    const int t = threadIdx.x;
    const int n = blockIdx.x * BLOCK + t;

    if (n < N) {
        const float x = inp[n * 3 + 0];
        const float y = inp[n * 3 + 1];
        const float z = inp[n * 3 + 2];

#pragma unroll
        for (int l = 0; l < NLEV; ++l) {
            const int R = kRes[l];
            const bool HASH = (l >= 5);
            const float scale = (float)(R - 1);
            const float px = x * scale, py = y * scale, pz = z * scale;
            const float fx = floorf(px), fy = floorf(py), fz = floorf(pz);
            const float wx = px - fx, wy = py - fy, wz = pz - fz;
            const unsigned ix = (unsigned)fx, iy = (unsigned)fy,
                           iz = (unsigned)fz;
            unsigned x0, x1, y0, y1, z0, z1;
            if (HASH) {
                x0 = ix;      x1 = ix + 1u;
                y0 = iy * P1; y1 = y0 + P1;
                z0 = iz * P2; z1 = z0 + P2;
            } else {
                const unsigned Ru = (unsigned)R, R2 = Ru * Ru;
                x0 = ix;      x1 = ix + 1u;
                y0 = iy * Ru; y1 = y0 + Ru;
                z0 = iz * R2; z1 = z0 + R2;
            }
            unsigned idx[8];
            if (HASH) {
                idx[0] = (x0 ^ y0 ^ z0) & HMASK; idx[1] = (x1 ^ y0 ^ z0) & HMASK;
                idx[2] = (x0 ^ y1 ^ z0) & HMASK; idx[3] = (x1 ^ y1 ^ z0) & HMASK;
                idx[4] = (x0 ^ y0 ^ z1) & HMASK; idx[5] = (x1 ^ y0 ^ z1) & HMASK;
                idx[6] = (x0 ^ y1 ^ z1) & HMASK; idx[7] = (x1 ^ y1 ^ z1) & HMASK;
            } else {
                idx[0] = x0 + y0 + z0; idx[1] = x1 + y0 + z0;
                idx[2] = x0 + y1 + z0; idx[3] = x1 + y1 + z0;
                idx[4] = x0 + y0 + z1; idx[5] = x1 + y0 + z1;
                idx[6] = x0 + y1 + z1; idx[7] = x1 + y1 + z1;
            }
            float ex[8], ey[8];
            if (PACKED) {
                const unsigned* eb =
                    reinterpret_cast<const unsigned*>(table) + kOff[l];
#pragma unroll
                for (int c = 0; c < 8; ++c) {
                    unsigned uu = eb[idx[c]];
                    ex[c] = lo2f(uu); ey[c] = hi2f(uu);
                }
            } else {
                const float2* eb =
                    reinterpret_cast<const float2*>(table) + kOff[l];
#pragma unroll
                for (int c = 0; c < 8; ++c) {
                    float2 e = eb[idx[c]]; ex[c] = e.x; ey[c] = e.y;
                }
            }
            const float w0x = 1.0f - wx, w0y = 1.0f - wy, w0z = 1.0f - wz;
            const float w00 = w0x * w0y, w10 = wx * w0y;
            const float w01 = w0x * wy,  w11 = wx * wy;
            const float wt[8] = {w00 * w0z, w10 * w0z, w01 * w0z, w11 * w0z,
                                 w00 * wz,  w10 * wz,  w01 * wz,  w11 * wz};
            float sx = 0.0f, sy = 0.0f;
#pragma unroll
            for (int c = 0; c < 8; ++c) {
                sx = fmaf(wt[c], ex[c], sx);
                sy = fmaf(wt[c], ey[c], sy);
            }
            s_out[t * 25 + 2 * l + 0] = sx;
            s_out[t * 25 + 2 * l + 1] = sy;
        }
    }
    __syncthreads();
    const long long base = (long long)blockIdx.x * (BLOCK * 24);
    const long long lim = (long long)N * 24;
#pragma unroll
    for (int k = 0; k < 24; ++k) {
        const int g = k * BLOCK + t;
        const long long gg = base + g;
        if (gg < lim) {
            const int nl = g / 24;
            const int j = g - nl * 24;
            out[gg] = s_out[nl * 25 + j];
        }
    }
}

extern "C" void kernel_launch(void* const* d_in, const int* in_sizes, int n_in,
                              void* d_out, int out_size, void* d_ws, size_t ws_size,
                              hipStream_t stream) {
    const float* inputs = (const float*)d_in[0];
    const float* embeddings = (const float*)d_in[1];
    // d_in[2]/d_in[3] (offsets/resolutions) are compile-time constants here.
    float* out = (float*)d_out;

    const int N = in_sizes[0] / 3;            // 2,000,000
    const int total = in_sizes[1] / 2;        // 4,078,528 table entries

    const size_t quad_bytes = (size_t)DENSE_A_END * 16;           // 2.34 MB
    const size_t pair4_bytes = (size_t)L4_SIZE * 8;               // 2.0 MB
    const size_t packed_bytes = (size_t)total * sizeof(unsigned); // 16.3 MB
    const size_t stage_bytes = (size_t)NLEV * N * sizeof(unsigned); // 96 MB

    const int ngrid = (N + BLOCK - 1) / BLOCK;
    const int grid2 = (N / 2 + BLOCK - 1) / BLOCK;  // PPT=2 kernels

    if (ws_size >= quad_bytes + pair4_bytes + packed_bytes + stage_bytes) {
        char* w = (char*)d_ws;
        uint4* quad = (uint4*)w;                  w += quad_bytes;
        u32x2* pair4 = (u32x2*)w;                 w += pair4_bytes;
        unsigned* packed = (unsigned*)w;          w += packed_bytes;
        unsigned* stage = (unsigned*)w;

        pack_table_kernel<<<(total + BLOCK - 1) / BLOCK, BLOCK, 0, stream>>>(
            (const float2*)embeddings, packed, total);
        pack_quad_kernel<<<(DENSE_A_END + BLOCK - 1) / BLOCK, BLOCK, 0, stream>>>(
            (const float2*)embeddings, quad);
        pack_pair4_kernel<<<(L4_SIZE + BLOCK - 1) / BLOCK, BLOCK, 0, stream>>>(
            (const float2*)embeddings, pair4);

        dense_a_kernel<<<grid2, BLOCK, 0, stream>>>(inputs, quad, stage, N);
        dense_b_kernel<<<grid2, BLOCK, 0, stream>>>(inputs, pair4,
                                                    stage + 4LL * N, N);
        hash_kernel<5><<<grid2, BLOCK, 0, stream>>>(inputs, packed, stage + 5LL * N, N);
        hash_kernel<6><<<grid2, BLOCK, 0, stream>>>(inputs, packed, stage + 6LL * N, N);
        hash_kernel<7><<<grid2, BLOCK, 0, stream>>>(inputs, packed, stage + 7LL * N, N);
        hash_kernel<8><<<grid2, BLOCK, 0, stream>>>(inputs, packed, stage + 8LL * N, N);
        hash_kernel<9><<<grid2, BLOCK, 0, stream>>>(inputs, packed, stage + 9LL * N, N);
        hash_kernel<10><<<grid2, BLOCK, 0, stream>>>(inputs, packed, stage + 10LL * N, N);
        hash_kernel<11><<<grid2, BLOCK, 0, stream>>>(inputs, packed, stage + 11LL * N, N);
        assemble_kernel<<<ngrid, BLOCK, 0, stream>>>(stage, out, N);
    } else if (ws_size >= packed_bytes) {
        unsigned* packed = (unsigned*)d_ws;
        pack_table_kernel<<<(total + BLOCK - 1) / BLOCK, BLOCK, 0, stream>>>(
            (const float2*)embeddings, packed, total);
        fused_kernel<1><<<ngrid, BLOCK, 0, stream>>>(inputs, packed, out, N);
    } else {
        fused_kernel<0><<<ngrid, BLOCK, 0, stream>>>(inputs, embeddings, out, N);
    }
}

// Round 10
// 490.346 us; speedup vs baseline: 1.3537x; 1.0812x over previous
//
#include <hip/hip_runtime.h>
#include <hip/hip_fp16.h>

// Instant-NGP grid encoder, MI355X (gfx950).
// N=2,000,000 points [N,3] f32 in [0,1); 12 levels, F=2; out [N,24] f32.
// res: 16,23,32,46,64,92,128,184,256,368,512,736; hash iff r^3>2^19
// (levels 5..11, each exactly 2^19 entries -> & 0x7FFFF). Dense: no modulo.
//
// Round-10: ONE mega-kernel, level-major blockIdx ordering.
//   Round-9's 9 serial compute dispatches each paid a launch gap + a full
//   occupancy drain-tail. Blocks dispatch in blockIdx order, so a single
//   grid with task = blockIdx/CB keeps the level-phased L2 locality
//   (resident window ~2048 blocks spans <=2 levels' tables) while removing
//   8 gaps + 8 tails. Inner loops identical to round 9 (isolates the
//   dispatch-structure variable); hash levels take runtime scale/offset.

namespace {
constexpr int NLEV = 12;
constexpr int BLOCK = 256;
constexpr int TOTAL = 4078528;        // table entries
constexpr int DENSE_A_END = 146368;   // levels 0..3
constexpr int L4_SIZE = 262144;       // level 4 (64^3)
constexpr unsigned P1 = 2654435761u;
constexpr unsigned P2 = 805459861u;
constexpr unsigned HMASK = (1u << 19) - 1u;

__device__ __constant__ constexpr int kRes[NLEV] = {
    16, 23, 32, 46, 64, 92, 128, 184, 256, 368, 512, 736};
__device__ __constant__ constexpr int kOff[NLEV] = {
    0, 4096, 16264, 49032, 146368, 408512,
    932800, 1457088, 1981376, 2505664, 3029952, 3554240};

typedef float    f32x2 __attribute__((ext_vector_type(2)));
typedef unsigned u32x2 __attribute__((ext_vector_type(2)));

__device__ __forceinline__ unsigned pkh2(float a, float b) {
    __half2 h = __floats2half2_rn(a, b);
    return *reinterpret_cast<unsigned*>(&h);
}
__device__ __forceinline__ float lo2f(unsigned u) {
    __half2 h = *reinterpret_cast<__half2*>(&u);
    return __low2float(h);
}
__device__ __forceinline__ float hi2f(unsigned u) {
    __half2 h = *reinterpret_cast<__half2*>(&u);
    return __high2float(h);
}
}  // namespace

// ---- fused pre-pass: packed (all), quad (levels 0-3), pair4 (level 4) ----
__global__ void __launch_bounds__(BLOCK)
pack_all_kernel(const float2* __restrict__ emb,
                unsigned* __restrict__ packed,
                uint4* __restrict__ quad,
                u32x2* __restrict__ pair4, int total)
{
    int i = blockIdx.x * BLOCK + threadIdx.x;
    if (i >= total) return;
    float2 v = emb[i];
    packed[i] = pkh2(v.x, v.y);
    if (i < DENSE_A_END) {
        int R = (i < 4096) ? 16 : (i < 16264) ? 23 : (i < 49032) ? 32 : 46;
        float2 e1 = emb[i + 1];
        float2 e2 = emb[i + R];
        float2 e3 = emb[i + R + 1];
        uint4 q;
        q.x = pkh2(v.x, v.y);  q.y = pkh2(e1.x, e1.y);
        q.z = pkh2(e2.x, e2.y); q.w = pkh2(e3.x, e3.y);
        quad[i] = q;
    }
    if (i < L4_SIZE) {
        int g = DENSE_A_END + i;
        float2 a = emb[g];
        float2 b = emb[g + 1];
        u32x2 o; o.x = pkh2(a.x, a.y); o.y = pkh2(b.x, b.y);
        pair4[i] = o;
    }
}

// ---- hash level encode, runtime scale; pt pre-offset to level base ----
__device__ __forceinline__ unsigned
encode_hash_rt(float x, float y, float z, const unsigned* __restrict__ pt,
               float scale)
{
    const float px = x * scale, py = y * scale, pz = z * scale;
    const float fx = floorf(px), fy = floorf(py), fz = floorf(pz);
    const float rx = px - fx, ry = py - fy, rz = pz - fz;
    const unsigned ix = (unsigned)fx, iy = (unsigned)fy, iz = (unsigned)fz;
    const unsigned yA = iy * P1, yB = yA + P1;
    const unsigned zA = iz * P2, zB = zA + P2;
    const unsigned h00 = (ix ^ yA ^ zA) & HMASK;
    const unsigned h10 = (ix ^ yB ^ zA) & HMASK;
    const unsigned h01 = (ix ^ yA ^ zB) & HMASK;
    const unsigned h11 = (ix ^ yB ^ zB) & HMASK;

    const u32x2* pt2 = reinterpret_cast<const u32x2*>(pt);
    const u32x2 q00 = pt2[h00 >> 1];
    const u32x2 q10 = pt2[h10 >> 1];
    const u32x2 q01 = pt2[h01 >> 1];
    const u32x2 q11 = pt2[h11 >> 1];

    unsigned e00 = (h00 & 1) ? q00.y : q00.x;
    unsigned e10 = (h10 & 1) ? q10.y : q10.x;
    unsigned e01 = (h01 & 1) ? q01.y : q01.x;
    unsigned e11 = (h11 & 1) ? q11.y : q11.x;
    unsigned f00 = (h00 & 1) ? q00.x : q00.y;
    unsigned f10 = (h10 & 1) ? q10.x : q10.y;
    unsigned f01 = (h01 & 1) ? q01.x : q01.y;
    unsigned f11 = (h11 & 1) ? q11.x : q11.y;

    if (ix & 1u) {  // odd ix: sibling word is ix-1; need real ix+1 entries
        const unsigned xo = ix + 1u;
        f00 = pt[(xo ^ yA ^ zA) & HMASK];
        f10 = pt[(xo ^ yB ^ zA) & HMASK];
        f01 = pt[(xo ^ yA ^ zB) & HMASK];
        f11 = pt[(xo ^ yB ^ zB) & HMASK];
    }

    const float wx0 = 1.0f - rx, wx1 = rx;
    const float wy0 = 1.0f - ry, wy1 = ry;
    const float wz0 = 1.0f - rz, wz1 = rz;
    const float w00 = wy0 * wz0, w10 = wy1 * wz0;
    const float w01 = wy0 * wz1, w11 = wy1 * wz1;
    float sx = 0.0f, sy = 0.0f;
    sx = fmaf(w00 * wx0, lo2f(e00), fmaf(w00 * wx1, lo2f(f00), sx));
    sy = fmaf(w00 * wx0, hi2f(e00), fmaf(w00 * wx1, hi2f(f00), sy));
    sx = fmaf(w10 * wx0, lo2f(e10), fmaf(w10 * wx1, lo2f(f10), sx));
    sy = fmaf(w10 * wx0, hi2f(e10), fmaf(w10 * wx1, hi2f(f10), sy));
    sx = fmaf(w01 * wx0, lo2f(e01), fmaf(w01 * wx1, lo2f(f01), sx));
    sy = fmaf(w01 * wx0, hi2f(e01), fmaf(w01 * wx1, hi2f(f01), sy));
    sx = fmaf(w11 * wx0, lo2f(e11), fmaf(w11 * wx1, lo2f(f11), sx));
    sy = fmaf(w11 * wx0, hi2f(e11), fmaf(w11 * wx1, hi2f(f11), sy));
    return pkh2(sx, sy);
}

// ---- MEGA: blocks [0,CB)=dense_a, [CB,2CB)=dense_b, [2CB,9CB)=hash5..11 ----
__global__ void __launch_bounds__(BLOCK)
mega_kernel(const float* __restrict__ inp,
            const uint4* __restrict__ quad,
            const u32x2* __restrict__ pair4,
            const unsigned* __restrict__ packed,
            unsigned* __restrict__ stage, int N, int CB)
{
    const int b = blockIdx.x;
    const int t = b / CB;            // task id (block-uniform)
    const int chunk = b - t * CB;
    const int g = chunk * BLOCK + threadIdx.x;   // point-pair index
    const int p0 = 2 * g;
    if (p0 >= N) return;
    const bool two = (p0 + 1 < N);

    // 6 consecutive floats = 2 points (aligned 8B vector loads)
    const f32x2* ip2 = reinterpret_cast<const f32x2*>(inp);
    f32x2 v0 = ip2[3 * g + 0];
    f32x2 v1, v2;
    if (two) { v1 = ip2[3 * g + 1]; v2 = ip2[3 * g + 2]; }
    else { v1.x = inp[3 * p0 + 2]; v1.y = 0.0f; v2.x = 0.0f; v2.y = 0.0f; }
    const float X[2] = {v0.x, v1.y};
    const float Y[2] = {v0.y, v2.x};
    const float Z[2] = {v1.x, v2.y};

    if (t == 0) {
        // dense levels 0..3, quad gathers
#pragma unroll
        for (int l = 0; l < 4; ++l) {
            const unsigned R = (unsigned)kRes[l];
            const unsigned R2 = R * R;
            const float scale = (float)(kRes[l] - 1);
            const uint4* qt = quad + kOff[l];
            u32x2 res;
#pragma unroll
            for (int k = 0; k < 2; ++k) {
                const float px = X[k] * scale, py = Y[k] * scale,
                            pz = Z[k] * scale;
                const float fx = floorf(px), fy = floorf(py), fz = floorf(pz);
                const float rx = px - fx, ry = py - fy, rz = pz - fz;
                const unsigned ix = (unsigned)fx, iy = (unsigned)fy,
                               iz = (unsigned)fz;
                const unsigned base = ix + iy * R + iz * R2;
                const uint4 q0 = qt[base];
                const uint4 q1 = qt[base + R2];
                const float wx0 = 1.0f - rx, wx1 = rx;
                const float wy0 = 1.0f - ry, wy1 = ry;
                const float wz0 = 1.0f - rz, wz1 = rz;
                const float ex00 = wx0 * lo2f(q0.x) + wx1 * lo2f(q0.y);
                const float ey00 = wx0 * hi2f(q0.x) + wx1 * hi2f(q0.y);
                const float ex10 = wx0 * lo2f(q0.z) + wx1 * lo2f(q0.w);
                const float ey10 = wx0 * hi2f(q0.z) + wx1 * hi2f(q0.w);
                const float ex01 = wx0 * lo2f(q1.x) + wx1 * lo2f(q1.y);
                const float ey01 = wx0 * hi2f(q1.x) + wx1 * hi2f(q1.y);
                const float ex11 = wx0 * lo2f(q1.z) + wx1 * lo2f(q1.w);
                const float ey11 = wx0 * hi2f(q1.z) + wx1 * hi2f(q1.w);
                const float sx = wz0 * (wy0 * ex00 + wy1 * ex10) +
                                 wz1 * (wy0 * ex01 + wy1 * ex11);
                const float sy = wz0 * (wy0 * ey00 + wy1 * ey10) +
                                 wz1 * (wy0 * ey01 + wy1 * ey11);
                res[k] = pkh2(sx, sy);
            }
            if (two) {
                __builtin_nontemporal_store(
                    res,
                    reinterpret_cast<u32x2*>(&stage[(long long)l * N + p0]));
            } else {
                __builtin_nontemporal_store(res.x,
                                            &stage[(long long)l * N + p0]);
            }
        }
    } else if (t == 1) {
        // dense level 4 (64^3), pair gathers
        constexpr unsigned R = 64, R2 = 4096;
        constexpr float scale = 63.0f;
        u32x2 res;
#pragma unroll
        for (int k = 0; k < 2; ++k) {
            const float px = X[k] * scale, py = Y[k] * scale, pz = Z[k] * scale;
            const float fx = floorf(px), fy = floorf(py), fz = floorf(pz);
            const float rx = px - fx, ry = py - fy, rz = pz - fz;
            const unsigned ix = (unsigned)fx, iy = (unsigned)fy,
                           iz = (unsigned)fz;
            const unsigned base = ix + iy * R + iz * R2;
            const u32x2 q00 = pair4[base];
            const u32x2 q10 = pair4[base + R];
            const u32x2 q01 = pair4[base + R2];
            const u32x2 q11 = pair4[base + R2 + R];
            const float wx0 = 1.0f - rx, wx1 = rx;
            const float wy0 = 1.0f - ry, wy1 = ry;
            const float wz0 = 1.0f - rz, wz1 = rz;
            const float w00 = wy0 * wz0, w10 = wy1 * wz0;
            const float w01 = wy0 * wz1, w11 = wy1 * wz1;
            float sx = 0.0f, sy = 0.0f;
            sx = fmaf(w00 * wx0, lo2f(q00.x), fmaf(w00 * wx1, lo2f(q00.y), sx));
            sy = fmaf(w00 * wx0, hi2f(q00.x), fmaf(w00 * wx1, hi2f(q00.y), sy));
            sx = fmaf(w10 * wx0, lo2f(q10.x), fmaf(w10 * wx1, lo2f(q10.y), sx));
            sy = fmaf(w10 * wx0, hi2f(q10.x), fmaf(w10 * wx1, hi2f(q10.y), sy));
            sx = fmaf(w01 * wx0, lo2f(q01.x), fmaf(w01 * wx1, lo2f(q01.y), sx));
            sy = fmaf(w01 * wx0, hi2f(q01.x), fmaf(w01 * wx1, hi2f(q01.y), sy));
            sx = fmaf(w11 * wx0, lo2f(q11.x), fmaf(w11 * wx1, lo2f(q11.y), sx));
            sy = fmaf(w11 * wx0, hi2f(q11.x), fmaf(w11 * wx1, hi2f(q11.y), sy));
            res[k] = pkh2(sx, sy);
        }
        unsigned* s4 = stage + 4LL * N;
        if (two) {
            __builtin_nontemporal_store(res,
                                        reinterpret_cast<u32x2*>(&s4[p0]));
        } else {
            __builtin_nontemporal_store(res.x, &s4[p0]);
        }
    } else {
        // hash level L = t + 3 (t=2..8 -> L=5..11)
        const int L = t + 3;
        const float scale = (float)(kRes[L] - 1);
        const unsigned* pt = packed + kOff[L];
        u32x2 res;
        res.x = encode_hash_rt(X[0], Y[0], Z[0], pt, scale);
        res.y = two ? encode_hash_rt(X[1], Y[1], Z[1], pt, scale) : 0u;
        unsigned* sl = stage + (long long)L * N;
        if (two) {
            __builtin_nontemporal_store(res,
                                        reinterpret_cast<u32x2*>(&sl[p0]));
        } else {
            __builtin_nontemporal_store(res.x, &sl[p0]);
        }
    }
}

// ---- final: [12][N] fp16x2 -> [N][24] f32, LDS transpose ----
__global__ void __launch_bounds__(BLOCK)
assemble_kernel(const unsigned* __restrict__ lvl, float* __restrict__ out,
                int N)
{
    __shared__ float s_out[BLOCK * 25];
    const int t = threadIdx.x;
    const int n = blockIdx.x * BLOCK + t;

    if (n < N) {
#pragma unroll
        for (int l = 0; l < NLEV; ++l) {
            unsigned u = __builtin_nontemporal_load(&lvl[(long long)l * N + n]);
            s_out[t * 25 + 2 * l + 0] = lo2f(u);
            s_out[t * 25 + 2 * l + 1] = hi2f(u);
        }
    }
    __syncthreads();

    const long long base = (long long)blockIdx.x * (BLOCK * 24);
    const long long lim = (long long)N * 24;
#pragma unroll
    for (int k = 0; k < 24; ++k) {
        const int g = k * BLOCK + t;
        const long long gg = base + g;
        if (gg < lim) {
            const int nl = g / 24;   // magic-mul division
            const int j = g - nl * 24;
            __builtin_nontemporal_store(s_out[nl * 25 + j], &out[gg]);
        }
    }
}

// ---- fallback: fused single-kernel (ws too small for staging) ----
template <int PACKED>
__global__ void __launch_bounds__(BLOCK, 4)
fused_kernel(const float* __restrict__ inp, const void* __restrict__ table,
             float* __restrict__ out, int N)
{
    __shared__ float s_out[BLOCK * 25];
    const int t = threadIdx.x;
    const int n = blockIdx.x * BLOCK + t;

    if (n < N) {
        const float x = inp[n * 3 + 0];
        const float y = inp[n * 3 + 1];
        const float z = inp[n * 3 + 2];

#pragma unroll
        for (int l = 0; l < NLEV; ++l) {
            const int R = kRes[l];
            const bool HASH = (l >= 5);
            const float scale = (float)(R - 1);
            const float px = x * scale, py = y * scale, pz = z * scale;
            const float fx = floorf(px), fy = floorf(py), fz = floorf(pz);
            const float wx = px - fx, wy = py - fy, wz = pz - fz;
            const unsigned ix = (unsigned)fx, iy = (unsigned)fy,
                           iz = (unsigned)fz;
            unsigned x0, x1, y0, y1, z0, z1;
            if (HASH) {
                x0 = ix;      x1 = ix + 1u;
                y0 = iy * P1; y1 = y0 + P1;
                z0 = iz * P2; z1 = z0 + P2;
            } else {
                const unsigned Ru = (unsigned)R, R2 = Ru * Ru;
                x0 = ix;      x1 = ix + 1u;
                y0 = iy * Ru; y1 = y0 + Ru;
                z0 = iz * R2; z1 = z0 + R2;
            }
            unsigned idx[8];
            if (HASH) {
                idx[0] = (x0 ^ y0 ^ z0) & HMASK; idx[1] = (x1 ^ y0 ^ z0) & HMASK;
                idx[2] = (x0 ^ y1 ^ z0) & HMASK; idx[3] = (x1 ^ y1 ^ z0) & HMASK;
                idx[4] = (x0 ^ y0 ^ z1) & HMASK; idx[5] = (x1 ^ y0 ^ z1) & HMASK;
                idx[6] = (x0 ^ y1 ^ z1) & HMASK; idx[7] = (x1 ^ y1 ^ z1) & HMASK;
            } else {
                idx[0] = x0 + y0 + z0; idx[1] = x1 + y0 + z0;
                idx[2] = x0 + y1 + z0; idx[3] = x1 + y1 + z0;
                idx[4] = x0 + y0 + z1; idx[5] = x1 + y0 + z1;
                idx[6] = x0 + y1 + z1; idx[7] = x1 + y1 + z1;
            }
            float ex[8], ey[8];
            if (PACKED) {
                const unsigned* eb =
                    reinterpret_cast<const unsigned*>(table) + kOff[l];
#pragma unroll
                for (int c = 0; c < 8; ++c) {
                    unsigned uu = eb[idx[c]];
                    ex[c] = lo2f(uu); ey[c] = hi2f(uu);
                }
            } else {
                const float2* eb =
                    reinterpret_cast<const float2*>(table) + kOff[l];
#pragma unroll
                for (int c = 0; c < 8; ++c) {
                    float2 e = eb[idx[c]]; ex[c] = e.x; ey[c] = e.y;
                }
            }
            const float w0x = 1.0f - wx, w0y = 1.0f - wy, w0z = 1.0f - wz;
            const float w00 = w0x * w0y, w10 = wx * w0y;
            const float w01 = w0x * wy,  w11 = wx * wy;
            const float wt[8] = {w00 * w0z, w10 * w0z, w01 * w0z, w11 * w0z,
                                 w00 * wz,  w10 * wz,  w01 * wz,  w11 * wz};
            float sx = 0.0f, sy = 0.0f;
#pragma unroll
            for (int c = 0; c < 8; ++c) {
                sx = fmaf(wt[c], ex[c], sx);
                sy = fmaf(wt[c], ey[c], sy);
            }
            s_out[t * 25 + 2 * l + 0] = sx;
            s_out[t * 25 + 2 * l + 1] = sy;
        }
    }
    __syncthreads();
    const long long base = (long long)blockIdx.x * (BLOCK * 24);
    const long long lim = (long long)N * 24;
#pragma unroll
    for (int k = 0; k < 24; ++k) {
        const int g = k * BLOCK + t;
        const long long gg = base + g;
        if (gg < lim) {
            const int nl = g / 24;
            const int j = g - nl * 24;
            out[gg] = s_out[nl * 25 + j];
        }
    }
}

extern "C" void kernel_launch(void* const* d_in, const int* in_sizes, int n_in,
                              void* d_out, int out_size, void* d_ws, size_t ws_size,
                              hipStream_t stream) {
    const float* inputs = (const float*)d_in[0];
    const float* embeddings = (const float*)d_in[1];
    // d_in[2]/d_in[3] (offsets/resolutions) are compile-time constants here.
    float* out = (float*)d_out;

    const int N = in_sizes[0] / 3;            // 2,000,000
    const int total = in_sizes[1] / 2;        // 4,078,528 table entries

    const size_t quad_bytes = (size_t)DENSE_A_END * 16;           // 2.34 MB
    const size_t pair4_bytes = (size_t)L4_SIZE * 8;               // 2.0 MB
    const size_t packed_bytes = (size_t)total * sizeof(unsigned); // 16.3 MB
    const size_t stage_bytes = (size_t)NLEV * N * sizeof(unsigned); // 96 MB

    const int ngrid = (N + BLOCK - 1) / BLOCK;

    if (ws_size >= quad_bytes + pair4_bytes + packed_bytes + stage_bytes) {
        char* w = (char*)d_ws;
        uint4* quad = (uint4*)w;                  w += quad_bytes;
        u32x2* pair4 = (u32x2*)w;                 w += pair4_bytes;
        unsigned* packed = (unsigned*)w;          w += packed_bytes;
        unsigned* stage = (unsigned*)w;

        pack_all_kernel<<<(total + BLOCK - 1) / BLOCK, BLOCK, 0, stream>>>(
            (const float2*)embeddings, packed, quad, pair4, total);

        const int pairs = (N + 1) / 2;
        const int CB = (pairs + BLOCK - 1) / BLOCK;   // chunks per task
        mega_kernel<<<9 * CB, BLOCK, 0, stream>>>(
            inputs, quad, pair4, packed, stage, N, CB);

        assemble_kernel<<<ngrid, BLOCK, 0, stream>>>(stage, out, N);
    } else if (ws_size >= packed_bytes) {
        unsigned* packed = (unsigned*)d_ws;
        // reuse pack_all with quad/pair4 disabled is not possible; plain pack:
        // pack into packed only via fused fallback path below.
        // (pack_all needs quad/pair4 buffers; emulate with packed-only kernel)
        // Simple: launch pack_all with dummy pointers into packed region is
        // unsafe; use the fused fallback directly on f32 table instead.
        fused_kernel<0><<<ngrid, BLOCK, 0, stream>>>(inputs, embeddings, out, N);
    } else {
        fused_kernel<0><<<ngrid, BLOCK, 0, stream>>>(inputs, embeddings, out, N);
    }
}